// Round 1
// baseline (2554.420 us; speedup 1.0000x reference)
//
#include <hip/hip_runtime.h>
#include <cstddef>
#include <cstdint>
#include <math.h>

#define B_   1024
#define L_   18
#define E_   300
#define H_   300
#define M_   (B_*L_)     // 18432 rows (b,l)
#define G4_  (4*H_)      // 1200
#define K2E_ (2*E_)      // 600

// workspace layout (float offsets)
#define OFF_XGF  ((size_t)0)
#define OFF_XGB  (OFF_XGF + (size_t)M_*G4_)          // 22,118,400
#define OFF_HF   (OFF_XGB + (size_t)M_*G4_)          // 44,236,800
#define OFF_HB   (OFF_HF  + (size_t)M_*H_)           // 49,766,400
#define OFF_CF   (OFF_HB  + (size_t)M_*H_)           // 55,296,000
#define OFF_CB   (OFF_CF  + (size_t)B_*H_)           // 55,603,200
#define OFF_AG   (OFF_CB  + (size_t)B_*H_)           // 55,910,400
#define OFF_WT4F (OFF_AG  + (size_t)B_*E_)           // 56,217,600
#define OFF_WT4B (OFF_WT4F + (size_t)H_*H_*4)        // 56,577,600
#define OFF_WBT  (OFF_WT4B + (size_t)H_*H_*4)        // 56,937,600
// end: 57,027,600 floats = 228.1 MB

#define VOFF ((size_t)M_*H_)  // v_g offset in d_out

__device__ __forceinline__ float sigmoidf_(float x) {
    return 1.0f / (1.0f + expf(-x));
}

// ---------------------------------------------------------------------------
// Weight re-layouts: WhhT4[k][j][gate] = Whh[(gate*300+j)*300 + k]
//                    WbT[k][o]          = Wb[o*300 + k]
// ---------------------------------------------------------------------------
__global__ void k_prep(const float* __restrict__ Whh_f,
                       const float* __restrict__ Whh_b,
                       const float* __restrict__ Wb,
                       float* __restrict__ WT4f,
                       float* __restrict__ WT4b,
                       float* __restrict__ WbT)
{
    int idx = blockIdx.x * 256 + threadIdx.x;
    if (idx < 360000) {
        int g = idx & 3;
        int j = (idx >> 2) % 300;
        int k = idx / 1200;
        WT4f[idx] = Whh_f[(g * 300 + j) * 300 + k];
    } else if (idx < 720000) {
        int q = idx - 360000;
        int g = q & 3;
        int j = (q >> 2) % 300;
        int k = q / 1200;
        WT4b[q] = Whh_b[(g * 300 + j) * 300 + k];
    } else if (idx < 810000) {
        int r = idx - 720000;
        int o = r % 300;
        int k = r / 300;
        WbT[r] = Wb[o * 300 + k];
    }
}

// ---------------------------------------------------------------------------
// a_g[b][e] = mean_l sem_table[sememes[b][l]][e]
// ---------------------------------------------------------------------------
__global__ __launch_bounds__(256) void k_ag(const int* __restrict__ sem,
                                            const float* __restrict__ sem_table,
                                            float* __restrict__ ag)
{
    int b = blockIdx.x;
    __shared__ int sm[L_];
    if (threadIdx.x < L_) sm[threadIdx.x] = sem[b * L_ + threadIdx.x];
    __syncthreads();
    for (int e = threadIdx.x; e < E_; e += 256) {
        float s = 0.f;
        #pragma unroll
        for (int l = 0; l < L_; ++l) s += sem_table[sm[l] * E_ + e];
        ag[(size_t)b * E_ + e] = s * (1.0f / (float)L_);
    }
}

// ---------------------------------------------------------------------------
// v_g = relu(a_g @ Wb^T + bb) -> d_out[VOFF + ...]
// 16 batch rows per block staged in LDS; WbT gives coalesced weight loads.
// ---------------------------------------------------------------------------
__global__ __launch_bounds__(256) void k_vg(const float* __restrict__ ag,
                                            const float* __restrict__ WbT,
                                            const float* __restrict__ bbv,
                                            float* __restrict__ out)
{
    int b0 = blockIdx.x * 16;
    __shared__ __align__(16) float ag_s[16 * E_];
    for (int idx = threadIdx.x; idx < 16 * E_; idx += 256)
        ag_s[idx] = ag[(size_t)b0 * E_ + idx];
    __syncthreads();
    for (int o = threadIdx.x; o < E_; o += 256) {
        float acc[16];
        #pragma unroll
        for (int i = 0; i < 16; ++i) acc[i] = 0.f;
        for (int k = 0; k < E_; ++k) {
            float w = WbT[k * E_ + o];
            #pragma unroll
            for (int i = 0; i < 16; ++i)
                acc[i] = fmaf(w, ag_s[i * E_ + k], acc[i]);
        }
        float bias = bbv[o];
        #pragma unroll
        for (int i = 0; i < 16; ++i) {
            float v = acc[i] + bias;
            out[VOFF + (size_t)(b0 + i) * E_ + o] = v > 0.f ? v : 0.f;
        }
    }
}

// ---------------------------------------------------------------------------
// xg_d = x @ Wih_d^T + (bih_d + bhh_d), d in {f,b} via blockIdx.z.
// x[m][k] is generated on the fly (gather fusion):
//   k < 300 : sememes[m]==0 ? sem_table[0][k] : word_table[word[b]][k]
//   k >= 300: sem_table[sememes[m]][k-300]
// Tiles: BM=64, BN=64, BK=24 (600 = 25*24), 256 threads, 4x4 per thread.
// ---------------------------------------------------------------------------
__global__ __launch_bounds__(256) void k_xg(const int* __restrict__ word,
                                            const int* __restrict__ sem,
                                            const float* __restrict__ word_table,
                                            const float* __restrict__ sem_table,
                                            const float* __restrict__ Wih_f,
                                            const float* __restrict__ Wih_b,
                                            const float* __restrict__ bih_f,
                                            const float* __restrict__ bhh_f,
                                            const float* __restrict__ bih_b,
                                            const float* __restrict__ bhh_b,
                                            float* __restrict__ xgf,
                                            float* __restrict__ xgb)
{
    const int BM = 64, BN = 64, BK = 24;
    int d = blockIdx.z;
    const float* Wih = d ? Wih_b : Wih_f;
    const float* bih = d ? bih_b : bih_f;
    const float* bhh = d ? bhh_b : bhh_f;
    float* xg = d ? xgb : xgf;

    int m0 = blockIdx.x * BM;
    int n0 = blockIdx.y * BN;

    __shared__ __align__(16) float As[BK][BM + 4];
    __shared__ __align__(16) float Bs[BK][BN + 4];
    __shared__ int   semL[BM];
    __shared__ int   wofL[BM];
    __shared__ float biasL[BN];

    int tid = threadIdx.x;
    if (tid < BM) {
        int m = m0 + tid;
        semL[tid] = sem[m];
        wofL[tid] = word[m / L_] * E_;
    }
    if (tid < BN) {
        int n = n0 + tid;
        biasL[tid] = (n < G4_) ? (bih[n] + bhh[n]) : 0.f;
    }
    __syncthreads();

    float acc[4][4];
    #pragma unroll
    for (int i = 0; i < 4; ++i)
        #pragma unroll
        for (int j = 0; j < 4; ++j) acc[i][j] = 0.f;

    int tx = tid & 15, ty = tid >> 4;

    for (int k0 = 0; k0 < K2E_; k0 += BK) {
        #pragma unroll
        for (int r = 0; r < 6; ++r) {
            int idx = tid + r * 256;          // < 1536 = 64*24
            int ml = idx / BK, kl = idx % BK;
            int k = k0 + kl;
            // A (gathered x)
            int smv = semL[ml];
            float av;
            if (k < E_) av = (smv == 0) ? sem_table[k] : word_table[wofL[ml] + k];
            else        av = sem_table[smv * E_ + (k - E_)];
            As[kl][ml] = av;
            // B (Wih row-major, coalesced along k)
            int n = n0 + ml;
            Bs[kl][ml] = (n < G4_) ? Wih[(size_t)n * K2E_ + k] : 0.f;
        }
        __syncthreads();
        #pragma unroll
        for (int kk = 0; kk < BK; ++kk) {
            float4 a4 = *(const float4*)&As[kk][ty * 4];
            float4 b4 = *(const float4*)&Bs[kk][tx * 4];
            float ar[4] = {a4.x, a4.y, a4.z, a4.w};
            float br[4] = {b4.x, b4.y, b4.z, b4.w};
            #pragma unroll
            for (int i = 0; i < 4; ++i)
                #pragma unroll
                for (int j = 0; j < 4; ++j)
                    acc[i][j] = fmaf(ar[i], br[j], acc[i][j]);
        }
        __syncthreads();
    }

    int n = n0 + tx * 4;
    if (n < G4_) {   // N=1200 divisible by 4 -> float4 fully in or out
        #pragma unroll
        for (int i = 0; i < 4; ++i) {
            int m = m0 + ty * 4 + i;
            float4 o;
            o.x = acc[i][0] + biasL[tx * 4 + 0];
            o.y = acc[i][1] + biasL[tx * 4 + 1];
            o.z = acc[i][2] + biasL[tx * 4 + 2];
            o.w = acc[i][3] + biasL[tx * 4 + 3];
            *(float4*)&xg[(size_t)m * G4_ + n] = o;
        }
    }
}

// ---------------------------------------------------------------------------
// One LSTM time-step, both directions (blockIdx.y). 8 batch rows per block.
// Thread j computes all 4 gates for unit j across 8 batch rows.
// WT layout: [k][j][gate] float4 -> one coalesced dwordx4 per (k, thread).
// ---------------------------------------------------------------------------
__global__ __launch_bounds__(320) void k_step(const float* __restrict__ xgf,
                                              const float* __restrict__ xgb,
                                              const float* __restrict__ WT4f,
                                              const float* __restrict__ WT4b,
                                              float* __restrict__ hf,
                                              float* __restrict__ hb,
                                              float* __restrict__ cf,
                                              float* __restrict__ cb,
                                              int s)
{
    int d = blockIdx.y;
    const float* xg = d ? xgb : xgf;
    const float* WT = d ? WT4b : WT4f;
    float* hout = d ? hb : hf;
    float* cbuf = d ? cb : cf;
    int t     = d ? (L_ - 1 - s) : s;
    int tprev = d ? (t + 1) : (t - 1);
    bool first = (s == 0);

    int b0 = blockIdx.x * 8;
    __shared__ __align__(16) float h_s[8][H_];

    int tid = threadIdx.x;
    if (!first) {
        for (int idx = tid; idx < 8 * H_; idx += 320) {
            int bb = idx / H_, j = idx % H_;
            h_s[bb][j] = hout[((size_t)(b0 + bb) * L_ + tprev) * H_ + j];
        }
    }
    __syncthreads();

    int j = tid;
    if (j < H_) {
        float acc[4][8];
        #pragma unroll
        for (int g = 0; g < 4; ++g)
            #pragma unroll
            for (int bb = 0; bb < 8; ++bb) acc[g][bb] = 0.f;

        if (!first) {
            for (int k = 0; k < H_; k += 4) {
                float4 w0 = *(const float4*)&WT[((size_t)(k + 0) * H_ + j) * 4];
                float4 w1 = *(const float4*)&WT[((size_t)(k + 1) * H_ + j) * 4];
                float4 w2 = *(const float4*)&WT[((size_t)(k + 2) * H_ + j) * 4];
                float4 w3 = *(const float4*)&WT[((size_t)(k + 3) * H_ + j) * 4];
                #pragma unroll
                for (int bb = 0; bb < 8; ++bb) {
                    float4 h4 = *(const float4*)&h_s[bb][k];
                    acc[0][bb] = fmaf(w0.x, h4.x, fmaf(w1.x, h4.y, fmaf(w2.x, h4.z, fmaf(w3.x, h4.w, acc[0][bb]))));
                    acc[1][bb] = fmaf(w0.y, h4.x, fmaf(w1.y, h4.y, fmaf(w2.y, h4.z, fmaf(w3.y, h4.w, acc[1][bb]))));
                    acc[2][bb] = fmaf(w0.z, h4.x, fmaf(w1.z, h4.y, fmaf(w2.z, h4.z, fmaf(w3.z, h4.w, acc[2][bb]))));
                    acc[3][bb] = fmaf(w0.w, h4.x, fmaf(w1.w, h4.y, fmaf(w2.w, h4.z, fmaf(w3.w, h4.w, acc[3][bb]))));
                }
            }
        }

        #pragma unroll
        for (int bb = 0; bb < 8; ++bb) {
            int b = b0 + bb;
            const float* xrow = xg + ((size_t)b * L_ + t) * G4_;
            float gi = acc[0][bb] + xrow[j];
            float gf = acc[1][bb] + xrow[H_ + j];
            float gg = acc[2][bb] + xrow[2 * H_ + j];
            float go = acc[3][bb] + xrow[3 * H_ + j];
            float iv = sigmoidf_(gi);
            float fv = sigmoidf_(gf);
            float gv = tanhf(gg);
            float ov = sigmoidf_(go);
            float cp = first ? 0.f : cbuf[(size_t)b * H_ + j];
            float cn = fmaf(fv, cp, iv * gv);
            float hn = ov * tanhf(cn);
            cbuf[(size_t)b * H_ + j] = cn;
            hout[((size_t)b * L_ + t) * H_ + j] = hn;
        }
    }
}

// ---------------------------------------------------------------------------
// V = relu([hf | hb] @ Wa^T + ba)   M=18432, K=600, N=300
// ---------------------------------------------------------------------------
__global__ __launch_bounds__(256) void k_out(const float* __restrict__ hf,
                                             const float* __restrict__ hb,
                                             const float* __restrict__ Wa,
                                             const float* __restrict__ ba,
                                             float* __restrict__ out)
{
    const int BM = 64, BN = 64, BK = 24;
    int m0 = blockIdx.x * BM;
    int n0 = blockIdx.y * BN;

    __shared__ __align__(16) float As[BK][BM + 4];
    __shared__ __align__(16) float Bs[BK][BN + 4];
    __shared__ float biasL[BN];

    int tid = threadIdx.x;
    if (tid < BN) {
        int n = n0 + tid;
        biasL[tid] = (n < H_) ? ba[n] : 0.f;
    }

    float acc[4][4];
    #pragma unroll
    for (int i = 0; i < 4; ++i)
        #pragma unroll
        for (int j = 0; j < 4; ++j) acc[i][j] = 0.f;

    int tx = tid & 15, ty = tid >> 4;

    for (int k0 = 0; k0 < K2E_; k0 += BK) {
        #pragma unroll
        for (int r = 0; r < 6; ++r) {
            int idx = tid + r * 256;
            int ml = idx / BK, kl = idx % BK;
            int k = k0 + kl;
            int m = m0 + ml;
            As[kl][ml] = (k < H_) ? hf[(size_t)m * H_ + k]
                                  : hb[(size_t)m * H_ + (k - H_)];
            int n = n0 + ml;
            Bs[kl][ml] = (n < H_) ? Wa[(size_t)n * K2E_ + k] : 0.f;
        }
        __syncthreads();
        #pragma unroll
        for (int kk = 0; kk < BK; ++kk) {
            float4 a4 = *(const float4*)&As[kk][ty * 4];
            float4 b4 = *(const float4*)&Bs[kk][tx * 4];
            float ar[4] = {a4.x, a4.y, a4.z, a4.w};
            float br[4] = {b4.x, b4.y, b4.z, b4.w};
            #pragma unroll
            for (int i = 0; i < 4; ++i)
                #pragma unroll
                for (int j = 0; j < 4; ++j)
                    acc[i][j] = fmaf(ar[i], br[j], acc[i][j]);
        }
        __syncthreads();
    }

    int n = n0 + tx * 4;
    if (n < H_) {   // 300 % 4 == 0 -> float4 fully in or out
        #pragma unroll
        for (int i = 0; i < 4; ++i) {
            int m = m0 + ty * 4 + i;
            float4 o;
            o.x = acc[i][0] + biasL[tx * 4 + 0];
            o.y = acc[i][1] + biasL[tx * 4 + 1];
            o.z = acc[i][2] + biasL[tx * 4 + 2];
            o.w = acc[i][3] + biasL[tx * 4 + 3];
            o.x = o.x > 0.f ? o.x : 0.f;
            o.y = o.y > 0.f ? o.y : 0.f;
            o.z = o.z > 0.f ? o.z : 0.f;
            o.w = o.w > 0.f ? o.w : 0.f;
            *(float4*)&out[(size_t)m * H_ + n] = o;
        }
    }
}

// ---------------------------------------------------------------------------
extern "C" void kernel_launch(void* const* d_in, const int* in_sizes, int n_in,
                              void* d_out, int out_size, void* d_ws, size_t ws_size,
                              hipStream_t stream) {
    const int*   word       = (const int*)  d_in[0];
    const int*   sem        = (const int*)  d_in[1];
    const float* word_table = (const float*)d_in[2];
    const float* sem_table  = (const float*)d_in[3];
    const float* Wih_f      = (const float*)d_in[4];
    const float* Whh_f      = (const float*)d_in[5];
    const float* bih_f      = (const float*)d_in[6];
    const float* bhh_f      = (const float*)d_in[7];
    const float* Wih_b      = (const float*)d_in[8];
    const float* Whh_b      = (const float*)d_in[9];
    const float* bih_b      = (const float*)d_in[10];
    const float* bhh_b      = (const float*)d_in[11];
    const float* Wa         = (const float*)d_in[12];
    const float* ba         = (const float*)d_in[13];
    const float* Wb         = (const float*)d_in[14];
    const float* bbv        = (const float*)d_in[15];

    float* out = (float*)d_out;
    float* ws  = (float*)d_ws;

    float* xgf  = ws + OFF_XGF;
    float* xgb  = ws + OFF_XGB;
    float* hf   = ws + OFF_HF;
    float* hb   = ws + OFF_HB;
    float* cf   = ws + OFF_CF;
    float* cb   = ws + OFF_CB;
    float* ag   = ws + OFF_AG;
    float* WT4f = ws + OFF_WT4F;
    float* WT4b = ws + OFF_WT4B;
    float* WbT  = ws + OFF_WBT;

    // 1. weight re-layouts
    k_prep<<<dim3((810000 + 255) / 256), dim3(256), 0, stream>>>(
        Whh_f, Whh_b, Wb, WT4f, WT4b, WbT);

    // 2. a_g + v_g
    k_ag<<<dim3(B_), dim3(256), 0, stream>>>(sem, sem_table, ag);
    k_vg<<<dim3(B_ / 16), dim3(256), 0, stream>>>(ag, WbT, bbv, out);

    // 3. input GEMMs (both directions), gather fused
    k_xg<<<dim3(M_ / 64, (G4_ + 63) / 64, 2), dim3(256), 0, stream>>>(
        word, sem, word_table, sem_table,
        Wih_f, Wih_b, bih_f, bhh_f, bih_b, bhh_b, xgf, xgb);

    // 4. 18 recurrent steps, fwd+bwd per launch
    for (int s = 0; s < L_; ++s) {
        k_step<<<dim3(B_ / 8, 2), dim3(320), 0, stream>>>(
            xgf, xgb, WT4f, WT4b, hf, hb, cf, cb, s);
    }

    // 5. output projection
    k_out<<<dim3(M_ / 64, (H_ + 63) / 64), dim3(256), 0, stream>>>(
        hf, hb, Wa, ba, out);
}

// Round 2
// 1288.308 us; speedup vs baseline: 1.9828x; 1.9828x over previous
//
#include <hip/hip_runtime.h>
#include <cstddef>
#include <cstdint>
#include <math.h>

#define B_   1024
#define L_   18
#define E_   300
#define H_   300
#define M_   (B_*L_)     // 18432 rows (b,l)
#define G4_  (4*H_)      // 1200
#define K2E_ (2*E_)      // 600

// GEMM (k_mm) dims: N = 2*G4_ = 2400, padded to 2432 (19 * 128); K padded to 608
#define NPAD 2432
#define KPAD 640          // Wcat row stride (elems); only k<608 read

// workspace layout (float offsets)
#define OFF_XGF  ((size_t)0)
#define OFF_XGB  (OFF_XGF + (size_t)M_*G4_)          // 22,118,400
#define OFF_HF   (OFF_XGB + (size_t)M_*G4_)          // 44,236,800
#define OFF_HB   (OFF_HF  + (size_t)M_*H_)           // 49,766,400
#define OFF_CF   (OFF_HB  + (size_t)M_*H_)           // 55,296,000
#define OFF_CB   (OFF_CF  + (size_t)B_*H_)           // 55,603,200
#define OFF_AG   (OFF_CB  + (size_t)B_*H_)           // 55,910,400
#define OFF_WT4F (OFF_AG  + (size_t)B_*E_)           // 56,217,600
#define OFF_WT4B (OFF_WT4F + (size_t)H_*H_*4)        // 56,577,600
#define OFF_WBT  (OFF_WT4B + (size_t)H_*H_*4)        // 56,937,600
// end: 57,027,600 floats = 228.1 MB
// Wcat (bf16, NPAD*KPAD = 3.11 MB) overlays OFF_HF: k_prep_w writes it,
// k_mm reads it, and only afterwards does k_step overwrite hf (stream order).

#define VOFF ((size_t)M_*H_)  // v_g offset in d_out

typedef short bf16x8 __attribute__((ext_vector_type(8)));
typedef float f32x4  __attribute__((ext_vector_type(4)));

__device__ __forceinline__ float sigmoidf_(float x) {
    return 1.0f / (1.0f + expf(-x));
}

__device__ __forceinline__ short f2bf(float f) {
    union { float f; uint32_t u; } c; c.f = f;
    uint32_t u = c.u + 0x7fffu + ((c.u >> 16) & 1u);   // RNE
    return (short)(u >> 16);
}

// ---------------------------------------------------------------------------
// Weight re-layouts: WhhT4[k][j][gate] = Whh[(gate*300+j)*300 + k]
//                    WbT[k][o]          = Wb[o*300 + k]
// ---------------------------------------------------------------------------
__global__ void k_prep(const float* __restrict__ Whh_f,
                       const float* __restrict__ Whh_b,
                       const float* __restrict__ Wb,
                       float* __restrict__ WT4f,
                       float* __restrict__ WT4b,
                       float* __restrict__ WbT)
{
    int idx = blockIdx.x * 256 + threadIdx.x;
    if (idx < 360000) {
        int g = idx & 3;
        int j = (idx >> 2) % 300;
        int k = idx / 1200;
        WT4f[idx] = Whh_f[(g * 300 + j) * 300 + k];
    } else if (idx < 720000) {
        int q = idx - 360000;
        int g = q & 3;
        int j = (q >> 2) % 300;
        int k = q / 1200;
        WT4b[q] = Whh_b[(g * 300 + j) * 300 + k];
    } else if (idx < 810000) {
        int r = idx - 720000;
        int o = r % 300;
        int k = r / 300;
        WbT[r] = Wb[o * 300 + k];
    }
}

// ---------------------------------------------------------------------------
// Wcat[n][k] (bf16): n<1200 -> Wih_f[n][k]; 1200<=n<2400 -> Wih_b[n-1200][k];
// zeros elsewhere (k>=600 or n>=2400).
// ---------------------------------------------------------------------------
__global__ __launch_bounds__(256) void k_prep_w(const float* __restrict__ Wih_f,
                                                const float* __restrict__ Wih_b,
                                                short* __restrict__ Wcat)
{
    int idx = blockIdx.x * 256 + threadIdx.x;   // < NPAD*KPAD
    int n = idx / KPAD;
    int k = idx - n * KPAD;
    float v = 0.f;
    if (k < K2E_) {
        if (n < G4_)            v = Wih_f[(size_t)n * K2E_ + k];
        else if (n < 2 * G4_)   v = Wih_b[(size_t)(n - G4_) * K2E_ + k];
    }
    Wcat[idx] = f2bf(v);
}

// ---------------------------------------------------------------------------
// a_g[b][e] = mean_l sem_table[sememes[b][l]][e]
// ---------------------------------------------------------------------------
__global__ __launch_bounds__(256) void k_ag(const int* __restrict__ sem,
                                            const float* __restrict__ sem_table,
                                            float* __restrict__ ag)
{
    int b = blockIdx.x;
    __shared__ int sm[L_];
    if (threadIdx.x < L_) sm[threadIdx.x] = sem[b * L_ + threadIdx.x];
    __syncthreads();
    for (int e = threadIdx.x; e < E_; e += 256) {
        float s = 0.f;
        #pragma unroll
        for (int l = 0; l < L_; ++l) s += sem_table[sm[l] * E_ + e];
        ag[(size_t)b * E_ + e] = s * (1.0f / (float)L_);
    }
}

// ---------------------------------------------------------------------------
// v_g = relu(a_g @ Wb^T + bb) -> d_out[VOFF + ...]
// ---------------------------------------------------------------------------
__global__ __launch_bounds__(256) void k_vg(const float* __restrict__ ag,
                                            const float* __restrict__ WbT,
                                            const float* __restrict__ bbv,
                                            float* __restrict__ out)
{
    int b0 = blockIdx.x * 16;
    __shared__ __align__(16) float ag_s[16 * E_];
    for (int idx = threadIdx.x; idx < 16 * E_; idx += 256)
        ag_s[idx] = ag[(size_t)b0 * E_ + idx];
    __syncthreads();
    for (int o = threadIdx.x; o < E_; o += 256) {
        float acc[16];
        #pragma unroll
        for (int i = 0; i < 16; ++i) acc[i] = 0.f;
        for (int k = 0; k < E_; ++k) {
            float w = WbT[k * E_ + o];
            #pragma unroll
            for (int i = 0; i < 16; ++i)
                acc[i] = fmaf(w, ag_s[i * E_ + k], acc[i]);
        }
        float bias = bbv[o];
        #pragma unroll
        for (int i = 0; i < 16; ++i) {
            float v = acc[i] + bias;
            out[VOFF + (size_t)(b0 + i) * E_ + o] = v > 0.f ? v : 0.f;
        }
    }
}

// ---------------------------------------------------------------------------
// k_mm: xg = x @ Wcat^T + bias   (bf16 MFMA)
//   M = 18432, N = 2432 (2400 valid), K = 608 (600 valid)
//   x[m][k] gathered on the fly from word/sem tables, cvt to bf16 in staging.
//   Tiles 128x128x32; 256 threads = 4 waves (2x2 of 64x64); 16 MFMAs/wave.
//   C/D layout (verified): col = lane&15, row = (lane>>4)*4 + reg.
// ---------------------------------------------------------------------------
#define BM 128
#define BN 128
#define BK 32
#define LDT 40    // LDS tile row stride (bf16 elems); 80 B: 16B-aligned, 2-way banks

__global__ __launch_bounds__(256) void k_mm(const int* __restrict__ word,
                                            const int* __restrict__ sem,
                                            const float* __restrict__ word_table,
                                            const float* __restrict__ sem_table,
                                            const short* __restrict__ Wcat,
                                            const float* __restrict__ bih_f,
                                            const float* __restrict__ bhh_f,
                                            const float* __restrict__ bih_b,
                                            const float* __restrict__ bhh_b,
                                            float* __restrict__ xgf,
                                            float* __restrict__ xgb)
{
    __shared__ __align__(16) short As[BM * LDT];
    __shared__ __align__(16) short Bs[BN * LDT];
    __shared__ int semL[BM];
    __shared__ int wofL[BM];

    const int m0 = blockIdx.x * BM;
    const int n0 = blockIdx.y * BN;
    const int tid = threadIdx.x;

    if (tid < BM) {
        int m = m0 + tid;
        semL[tid] = sem[m];
        wofL[tid] = word[m / L_] * E_;
    }
    __syncthreads();

    f32x4 acc[4][4];
    #pragma unroll
    for (int i = 0; i < 4; ++i)
        #pragma unroll
        for (int j = 0; j < 4; ++j)
            acc[i][j] = (f32x4){0.f, 0.f, 0.f, 0.f};

    const int wv   = tid >> 6;            // wave 0..3
    const int lane = tid & 63;
    const int wm   = (wv >> 1) * 64;      // wave M offset in tile
    const int wn   = (wv & 1) * 64;       // wave N offset in tile
    const int lm   = lane & 15;
    const int quad = lane >> 4;

    // staging assignment: thread -> row r, k-half h (16 elems)
    const int r  = tid >> 1;
    const int kh = (tid & 1) * 16;
    const int sv  = semL[r];
    const int wof = wofL[r];

    for (int k0 = 0; k0 < 608; k0 += BK) {
        // ---- stage A (gathered x, fp32 -> bf16) ----
        {
            const int kbase = k0 + kh;
            #pragma unroll
            for (int q = 0; q < 4; ++q) {
                int k = kbase + q * 4;
                float4 v;
                if (k < E_)
                    v = (sv == 0) ? *(const float4*)&sem_table[k]
                                  : *(const float4*)&word_table[wof + k];
                else if (k < K2E_)
                    v = *(const float4*)&sem_table[sv * E_ + (k - E_)];
                else
                    v = make_float4(0.f, 0.f, 0.f, 0.f);
                short4 s4;
                s4.x = f2bf(v.x); s4.y = f2bf(v.y);
                s4.z = f2bf(v.z); s4.w = f2bf(v.w);
                *(short4*)&As[r * LDT + kh + q * 4] = s4;
            }
        }
        // ---- stage B (Wcat bf16 direct copy) ----
        {
            const short* src = Wcat + (size_t)(n0 + r) * KPAD + k0 + kh;
            *(int4*)&Bs[r * LDT + kh + 0] = *(const int4*)&src[0];
            *(int4*)&Bs[r * LDT + kh + 8] = *(const int4*)&src[8];
        }
        __syncthreads();

        // ---- fragments + MFMA ----
        bf16x8 af[4], bfr[4];
        #pragma unroll
        for (int i = 0; i < 4; ++i)
            af[i] = *(const bf16x8*)&As[(wm + 16 * i + lm) * LDT + quad * 8];
        #pragma unroll
        for (int j = 0; j < 4; ++j)
            bfr[j] = *(const bf16x8*)&Bs[(wn + 16 * j + lm) * LDT + quad * 8];
        #pragma unroll
        for (int i = 0; i < 4; ++i)
            #pragma unroll
            for (int j = 0; j < 4; ++j)
                acc[i][j] = __builtin_amdgcn_mfma_f32_16x16x32_bf16(
                    af[i], bfr[j], acc[i][j], 0, 0, 0);
        __syncthreads();
    }

    // ---- epilogue: bias + route to xgf/xgb ----
    #pragma unroll
    for (int j = 0; j < 4; ++j) {
        int n = n0 + wn + 16 * j + lm;       // 16-aligned fragment column base
        if (n >= 2 * G4_) continue;          // padding columns
        float bias;
        float* dst;
        int col;
        if (n < G4_) { bias = bih_f[n] + bhh_f[n];              dst = xgf; col = n; }
        else         { bias = bih_b[n - G4_] + bhh_b[n - G4_];  dst = xgb; col = n - G4_; }
        #pragma unroll
        for (int i = 0; i < 4; ++i) {
            int mb = m0 + wm + 16 * i + quad * 4;
            #pragma unroll
            for (int reg = 0; reg < 4; ++reg)
                dst[(size_t)(mb + reg) * G4_ + col] = acc[i][j][reg] + bias;
        }
    }
}

// ---------------------------------------------------------------------------
// One LSTM time-step, both directions (blockIdx.y). 4 batch rows per block
// (512 blocks total -> 2 blocks/CU, 10 waves/CU for latency hiding).
// ---------------------------------------------------------------------------
#define SB 4   // batches per block
__global__ __launch_bounds__(320) void k_step(const float* __restrict__ xgf,
                                              const float* __restrict__ xgb,
                                              const float* __restrict__ WT4f,
                                              const float* __restrict__ WT4b,
                                              float* __restrict__ hf,
                                              float* __restrict__ hb,
                                              float* __restrict__ cf,
                                              float* __restrict__ cb,
                                              int s)
{
    int d = blockIdx.y;
    const float* xg = d ? xgb : xgf;
    const float* WT = d ? WT4b : WT4f;
    float* hout = d ? hb : hf;
    float* cbuf = d ? cb : cf;
    int t     = d ? (L_ - 1 - s) : s;
    int tprev = d ? (t + 1) : (t - 1);
    bool first = (s == 0);

    int b0 = blockIdx.x * SB;
    __shared__ __align__(16) float h_s[SB][H_];

    int tid = threadIdx.x;
    if (!first) {
        for (int idx = tid; idx < SB * H_; idx += 320) {
            int bb = idx / H_, j = idx % H_;
            h_s[bb][j] = hout[((size_t)(b0 + bb) * L_ + tprev) * H_ + j];
        }
    }
    __syncthreads();

    int j = tid;
    if (j < H_) {
        float acc[4][SB];
        #pragma unroll
        for (int g = 0; g < 4; ++g)
            #pragma unroll
            for (int bb = 0; bb < SB; ++bb) acc[g][bb] = 0.f;

        if (!first) {
            for (int k = 0; k < H_; k += 4) {
                float4 w0 = *(const float4*)&WT[((size_t)(k + 0) * H_ + j) * 4];
                float4 w1 = *(const float4*)&WT[((size_t)(k + 1) * H_ + j) * 4];
                float4 w2 = *(const float4*)&WT[((size_t)(k + 2) * H_ + j) * 4];
                float4 w3 = *(const float4*)&WT[((size_t)(k + 3) * H_ + j) * 4];
                #pragma unroll
                for (int bb = 0; bb < SB; ++bb) {
                    float4 h4 = *(const float4*)&h_s[bb][k];
                    acc[0][bb] = fmaf(w0.x, h4.x, fmaf(w1.x, h4.y, fmaf(w2.x, h4.z, fmaf(w3.x, h4.w, acc[0][bb]))));
                    acc[1][bb] = fmaf(w0.y, h4.x, fmaf(w1.y, h4.y, fmaf(w2.y, h4.z, fmaf(w3.y, h4.w, acc[1][bb]))));
                    acc[2][bb] = fmaf(w0.z, h4.x, fmaf(w1.z, h4.y, fmaf(w2.z, h4.z, fmaf(w3.z, h4.w, acc[2][bb]))));
                    acc[3][bb] = fmaf(w0.w, h4.x, fmaf(w1.w, h4.y, fmaf(w2.w, h4.z, fmaf(w3.w, h4.w, acc[3][bb]))));
                }
            }
        }

        #pragma unroll
        for (int bb = 0; bb < SB; ++bb) {
            int b = b0 + bb;
            const float* xrow = xg + ((size_t)b * L_ + t) * G4_;
            float gi = acc[0][bb] + xrow[j];
            float gf = acc[1][bb] + xrow[H_ + j];
            float gg = acc[2][bb] + xrow[2 * H_ + j];
            float go = acc[3][bb] + xrow[3 * H_ + j];
            float iv = sigmoidf_(gi);
            float fv = sigmoidf_(gf);
            float gv = tanhf(gg);
            float ov = sigmoidf_(go);
            float cp = first ? 0.f : cbuf[(size_t)b * H_ + j];
            float cn = fmaf(fv, cp, iv * gv);
            float hn = ov * tanhf(cn);
            cbuf[(size_t)b * H_ + j] = cn;
            hout[((size_t)b * L_ + t) * H_ + j] = hn;
        }
    }
}

// ---------------------------------------------------------------------------
// V = relu([hf | hb] @ Wa^T + ba)   M=18432, K=600, N=300  (fp32)
// ---------------------------------------------------------------------------
__global__ __launch_bounds__(256) void k_out(const float* __restrict__ hf,
                                             const float* __restrict__ hb,
                                             const float* __restrict__ Wa,
                                             const float* __restrict__ ba,
                                             float* __restrict__ out)
{
    const int TBM = 64, TBN = 64, TBK = 24;
    int m0 = blockIdx.x * TBM;
    int n0 = blockIdx.y * TBN;

    __shared__ __align__(16) float Asf[TBK][TBM + 4];
    __shared__ __align__(16) float Bsf[TBK][TBN + 4];
    __shared__ float biasL[TBN];

    int tid = threadIdx.x;
    if (tid < TBN) {
        int n = n0 + tid;
        biasL[tid] = (n < H_) ? ba[n] : 0.f;
    }

    float acc[4][4];
    #pragma unroll
    for (int i = 0; i < 4; ++i)
        #pragma unroll
        for (int j = 0; j < 4; ++j) acc[i][j] = 0.f;

    int tx = tid & 15, ty = tid >> 4;

    for (int k0 = 0; k0 < K2E_; k0 += TBK) {
        #pragma unroll
        for (int rr = 0; rr < 6; ++rr) {
            int idx = tid + rr * 256;
            int ml = idx / TBK, kl = idx % TBK;
            int k = k0 + kl;
            int m = m0 + ml;
            Asf[kl][ml] = (k < H_) ? hf[(size_t)m * H_ + k]
                                   : hb[(size_t)m * H_ + (k - H_)];
            int n = n0 + ml;
            Bsf[kl][ml] = (n < H_) ? Wa[(size_t)n * K2E_ + k] : 0.f;
        }
        __syncthreads();
        #pragma unroll
        for (int kk = 0; kk < TBK; ++kk) {
            float4 a4 = *(const float4*)&Asf[kk][ty * 4];
            float4 b4 = *(const float4*)&Bsf[kk][tx * 4];
            float ar[4] = {a4.x, a4.y, a4.z, a4.w};
            float br[4] = {b4.x, b4.y, b4.z, b4.w};
            #pragma unroll
            for (int i = 0; i < 4; ++i)
                #pragma unroll
                for (int j = 0; j < 4; ++j)
                    acc[i][j] = fmaf(ar[i], br[j], acc[i][j]);
        }
        __syncthreads();
    }

    int n = n0 + tx * 4;
    if (n < H_) {
        #pragma unroll
        for (int i = 0; i < 4; ++i) {
            int m = m0 + ty * 4 + i;
            float4 o;
            o.x = acc[i][0] + biasL[tx * 4 + 0];
            o.y = acc[i][1] + biasL[tx * 4 + 1];
            o.z = acc[i][2] + biasL[tx * 4 + 2];
            o.w = acc[i][3] + biasL[tx * 4 + 3];
            o.x = o.x > 0.f ? o.x : 0.f;
            o.y = o.y > 0.f ? o.y : 0.f;
            o.z = o.z > 0.f ? o.z : 0.f;
            o.w = o.w > 0.f ? o.w : 0.f;
            *(float4*)&out[(size_t)m * H_ + n] = o;
        }
    }
}

// ---------------------------------------------------------------------------
extern "C" void kernel_launch(void* const* d_in, const int* in_sizes, int n_in,
                              void* d_out, int out_size, void* d_ws, size_t ws_size,
                              hipStream_t stream) {
    const int*   word       = (const int*)  d_in[0];
    const int*   sem        = (const int*)  d_in[1];
    const float* word_table = (const float*)d_in[2];
    const float* sem_table  = (const float*)d_in[3];
    const float* Wih_f      = (const float*)d_in[4];
    const float* Whh_f      = (const float*)d_in[5];
    const float* bih_f      = (const float*)d_in[6];
    const float* bhh_f      = (const float*)d_in[7];
    const float* Wih_b      = (const float*)d_in[8];
    const float* Whh_b      = (const float*)d_in[9];
    const float* bih_b      = (const float*)d_in[10];
    const float* bhh_b      = (const float*)d_in[11];
    const float* Wa         = (const float*)d_in[12];
    const float* ba         = (const float*)d_in[13];
    const float* Wb         = (const float*)d_in[14];
    const float* bbv        = (const float*)d_in[15];

    float* out = (float*)d_out;
    float* ws  = (float*)d_ws;

    float* xgf  = ws + OFF_XGF;
    float* xgb  = ws + OFF_XGB;
    float* hf   = ws + OFF_HF;
    float* hb   = ws + OFF_HB;
    float* cf   = ws + OFF_CF;
    float* cb   = ws + OFF_CB;
    float* ag   = ws + OFF_AG;
    float* WT4f = ws + OFF_WT4F;
    float* WT4b = ws + OFF_WT4B;
    float* WbT  = ws + OFF_WBT;
    short* Wcat = (short*)(ws + OFF_HF);   // overlays hf until k_mm finishes

    // 1. weight re-layouts
    k_prep<<<dim3((810000 + 255) / 256), dim3(256), 0, stream>>>(
        Whh_f, Whh_b, Wb, WT4f, WT4b, WbT);
    k_prep_w<<<dim3((NPAD * KPAD) / 256), dim3(256), 0, stream>>>(
        Wih_f, Wih_b, Wcat);

    // 2. a_g + v_g
    k_ag<<<dim3(B_), dim3(256), 0, stream>>>(sem, sem_table, ag);
    k_vg<<<dim3(B_ / 16), dim3(256), 0, stream>>>(ag, WbT, bbv, out);

    // 3. input GEMM, both directions fused (bf16 MFMA), gather fused
    k_mm<<<dim3(M_ / BM, NPAD / BN), dim3(256), 0, stream>>>(
        word, sem, word_table, sem_table, Wcat,
        bih_f, bhh_f, bih_b, bhh_b, xgf, xgb);

    // 4. 18 recurrent steps, fwd+bwd per launch
    for (int s = 0; s < L_; ++s) {
        k_step<<<dim3(B_ / SB, 2), dim3(320), 0, stream>>>(
            xgf, xgb, WT4f, WT4b, hf, hb, cf, cb, s);
    }

    // 5. output projection
    k_out<<<dim3(M_ / 64, (H_ + 63) / 64), dim3(256), 0, stream>>>(
        hf, hb, Wa, ba, out);
}